// Round 1
// baseline (289.792 us; speedup 1.0000x reference)
//
#include <hip/hip_runtime.h>
#include <math.h>

#define NBLK 1024
#define K 5
#define D 384
#define D4 (D/4)   // 96 float4 per row
#define THREADS 256
#define GROUPS_PER_BLOCK (THREADS/16)   // 16 rows per block-iter
#define C1 (GROUPS_PER_BLOCK*K)         // 80 candidates per block
#define C2 (NBLK*K)                     // 5120 candidates total

__device__ __forceinline__ bool better(float v1, int r1, float v2, int r2) {
    // strictly larger value wins; on exact tie, smaller row index wins (jax top_k order)
    return (v1 > v2) || (v1 == v2 && r1 < r2);
}

// ---- kernel 0: 1/max(||q||, eps) ----
__global__ void qnorm_kernel(const float* __restrict__ q, float* __restrict__ invq) {
    int l = threadIdx.x;            // 64 threads
    float ss = 0.f;
    #pragma unroll
    for (int j = 0; j < 6; ++j) {
        float x = q[l + 64*j];
        ss += x * x;
    }
    #pragma unroll
    for (int m = 1; m < 64; m <<= 1) ss += __shfl_xor(ss, m);
    if (l == 0) invq[0] = 1.0f / fmaxf(sqrtf(ss), 1e-12f);
}

// ---- kernel 1: per-row cosine sim + per-block top-K ----
__global__ __launch_bounds__(THREADS) void sim_topk_kernel(
        const float* __restrict__ corpus, const float* __restrict__ q,
        const float* __restrict__ invq_p,
        float* __restrict__ bVals, int* __restrict__ bIdx, int N) {
    __shared__ float qs[D];
    float invq = invq_p[0];
    for (int i = threadIdx.x; i < D; i += THREADS) qs[i] = q[i] * invq;
    __syncthreads();
    const float4* q4 = reinterpret_cast<const float4*>(qs);

    const int lane16 = threadIdx.x & 15;
    const int group  = threadIdx.x >> 4;                 // 0..15
    const int ggid   = blockIdx.x * GROUPS_PER_BLOCK + group;
    const int gcount = gridDim.x * GROUPS_PER_BLOCK;

    float tv[K]; int ti[K];
    #pragma unroll
    for (int i = 0; i < K; ++i) { tv[i] = -INFINITY; ti[i] = 0x7fffffff; }

    for (int row = ggid; row < N; row += gcount) {
        const float4* r4 = reinterpret_cast<const float4*>(corpus + (size_t)row * D);
        float dot = 0.f, nrm = 0.f;
        #pragma unroll
        for (int j = 0; j < 6; ++j) {
            float4 x = r4[lane16 + 16*j];
            float4 w = q4[lane16 + 16*j];
            dot += x.x*w.x + x.y*w.y + x.z*w.z + x.w*w.w;
            nrm += x.x*x.x + x.y*x.y + x.z*x.z + x.w*x.w;
        }
        #pragma unroll
        for (int m = 1; m < 16; m <<= 1) {
            dot += __shfl_xor(dot, m);
            nrm += __shfl_xor(nrm, m);
        }
        if (lane16 == 0) {
            float sim = dot / fmaxf(sqrtf(nrm), 1e-12f);
            sim = fmaxf(sim, 1e-6f);           // clamp(min=1e-6); NaN propagates
            if (sim != sim) sim = 0.f;         // nan_to_num
            if (sim > tv[K-1]) {               // strict: equal keeps earlier row
                int j = K - 1;
                while (j > 0 && tv[j-1] < sim) { tv[j] = tv[j-1]; ti[j] = ti[j-1]; --j; }
                tv[j] = sim; ti[j] = row;
            }
        }
    }

    // block-level top-K over the 16 leaders' sorted lists
    __shared__ float cv[C1]; __shared__ int ci[C1];
    __shared__ float rv[THREADS]; __shared__ int ri[THREADS]; __shared__ int rs[THREADS];
    if (lane16 == 0) {
        #pragma unroll
        for (int i = 0; i < K; ++i) { cv[group*K + i] = tv[i]; ci[group*K + i] = ti[i]; }
    }
    __syncthreads();

    for (int r = 0; r < K; ++r) {
        float bv = -INFINITY; int bi = 0x7fffffff; int bslot = -1;
        for (int c = threadIdx.x; c < C1; c += THREADS)
            if (better(cv[c], ci[c], bv, bi)) { bv = cv[c]; bi = ci[c]; bslot = c; }
        rv[threadIdx.x] = bv; ri[threadIdx.x] = bi; rs[threadIdx.x] = bslot;
        __syncthreads();
        for (int s = THREADS/2; s > 0; s >>= 1) {
            if (threadIdx.x < s) {
                if (better(rv[threadIdx.x+s], ri[threadIdx.x+s], rv[threadIdx.x], ri[threadIdx.x])) {
                    rv[threadIdx.x] = rv[threadIdx.x+s];
                    ri[threadIdx.x] = ri[threadIdx.x+s];
                    rs[threadIdx.x] = rs[threadIdx.x+s];
                }
            }
            __syncthreads();
        }
        if (threadIdx.x == 0) {
            bVals[blockIdx.x*K + r] = rv[0];
            bIdx [blockIdx.x*K + r] = ri[0];
            if (rs[0] >= 0) cv[rs[0]] = -INFINITY;
        }
        __syncthreads();
    }
}

// ---- kernel 2: global top-K over block candidates ----
__global__ __launch_bounds__(THREADS) void final_topk_kernel(
        const float* __restrict__ bVals, const int* __restrict__ bIdx,
        float* __restrict__ out, int nC) {
    __shared__ float cv[C2]; __shared__ int ci[C2];
    __shared__ float rv[THREADS]; __shared__ int ri[THREADS]; __shared__ int rs[THREADS];
    for (int c = threadIdx.x; c < nC; c += THREADS) { cv[c] = bVals[c]; ci[c] = bIdx[c]; }
    __syncthreads();

    for (int r = 0; r < K; ++r) {
        float bv = -INFINITY; int bi = 0x7fffffff; int bslot = -1;
        for (int c = threadIdx.x; c < nC; c += THREADS)
            if (better(cv[c], ci[c], bv, bi)) { bv = cv[c]; bi = ci[c]; bslot = c; }
        rv[threadIdx.x] = bv; ri[threadIdx.x] = bi; rs[threadIdx.x] = bslot;
        __syncthreads();
        for (int s = THREADS/2; s > 0; s >>= 1) {
            if (threadIdx.x < s) {
                if (better(rv[threadIdx.x+s], ri[threadIdx.x+s], rv[threadIdx.x], ri[threadIdx.x])) {
                    rv[threadIdx.x] = rv[threadIdx.x+s];
                    ri[threadIdx.x] = ri[threadIdx.x+s];
                    rs[threadIdx.x] = rs[threadIdx.x+s];
                }
            }
            __syncthreads();
        }
        if (threadIdx.x == 0) {
            out[r]     = rv[0];
            out[K + r] = (float)ri[0];    // indices output read back as f32
            if (rs[0] >= 0) cv[rs[0]] = -INFINITY;
        }
        __syncthreads();
    }
}

extern "C" void kernel_launch(void* const* d_in, const int* in_sizes, int n_in,
                              void* d_out, int out_size, void* d_ws, size_t ws_size,
                              hipStream_t stream) {
    const float* q      = (const float*)d_in[0];
    const float* corpus = (const float*)d_in[1];
    const int N = in_sizes[1] / D;

    char* ws = (char*)d_ws;
    float* invq  = (float*)ws;                       // 1 float (256B slot)
    float* bVals = (float*)(ws + 256);               // NBLK*K floats
    int*   bIdx  = (int*)  (ws + 256 + NBLK*K*4);    // NBLK*K ints

    float* out = (float*)d_out;

    qnorm_kernel<<<1, 64, 0, stream>>>(q, invq);
    sim_topk_kernel<<<NBLK, THREADS, 0, stream>>>(corpus, q, invq, bVals, bIdx, N);
    final_topk_kernel<<<1, THREADS, 0, stream>>>(bVals, bIdx, out, NBLK*K);
}